// Round 7
// baseline (332.052 us; speedup 1.0000x reference)
//
#include <hip/hip_runtime.h>
#include <hip/hip_bf16.h>

#define N_NODES 50000
#define N_EDGES 800000
#define F_IN 512
#define HIDDEN 128
#define N_CLASSES 40
#define NSCAN 196    // ceil(50000/256)
#define CB 391       // count blocks in fused kernel (391*256*8 >= 800000)

typedef __attribute__((ext_vector_type(4))) float f32x4;
typedef __attribute__((ext_vector_type(8))) short s16x8;

// manual RNE f32 -> bf16
__device__ __forceinline__ unsigned bf16r(float f) {
    unsigned u = __float_as_uint(f);
    return (u + 0x7fffu + ((u >> 16) & 1u)) >> 16;
}
__device__ __forceinline__ unsigned pkbf(float lo, float hi) {
    return bf16r(lo) | (bf16r(hi) << 16);
}
__device__ __forceinline__ float bflo(unsigned u) { return __uint_as_float(u << 16); }
__device__ __forceinline__ float bfhi(unsigned u) { return __uint_as_float(u & 0xffff0000u); }

// ---------------- prep: pack W1/W2 into MFMA B-fragment layout (bf16) ------
__global__ void prep_kernel(const float* __restrict__ W1, const float* __restrict__ W2,
                            uint4* __restrict__ w1f, uint4* __restrict__ w2f) {
    int f = blockIdx.x * 256 + threadIdx.x;
    if (f < 8192) {
        int lane = f & 63, u = (f >> 6) & 7, c = f >> 9;
        int k0 = c * 32 + ((lane >> 4) << 3), n = u * 16 + (lane & 15);
        float v[8];
        #pragma unroll
        for (int j = 0; j < 8; ++j) v[j] = W1[(size_t)(k0 + j) * HIDDEN + n];
        uint4 o;
        o.x = pkbf(v[0], v[1]); o.y = pkbf(v[2], v[3]);
        o.z = pkbf(v[4], v[5]); o.w = pkbf(v[6], v[7]);
        w1f[f] = o;
    } else if (f < 8960) {
        int g = f - 8192;
        int lane = g & 63, u = (g >> 6) % 3, c = g / 192;
        int k0 = c * 32 + ((lane >> 4) << 3), n = u * 16 + (lane & 15);
        float v[8];
        #pragma unroll
        for (int j = 0; j < 8; ++j)
            v[j] = (n < N_CLASSES) ? W2[(size_t)(k0 + j) * N_CLASSES + n] : 0.0f;
        uint4 o;
        o.x = pkbf(v[0], v[1]); o.y = pkbf(v[2], v[3]);
        o.z = pkbf(v[4], v[5]); o.w = pkbf(v[6], v[7]);
        w2f[g] = o;
    }
}

// ---------------- fused: edge count/pos (391 blocks) + GEMM1 (782 blocks) --
__global__ __launch_bounds__(256) void fused_kernel(
    const float* __restrict__ x, const uint4* __restrict__ w1f,
    unsigned short* __restrict__ h1s,
    const int* __restrict__ row, const int* __restrict__ col,
    int* __restrict__ rowcnt, int* __restrict__ colcnt, int* __restrict__ pos8)
{
    __shared__ uint4 XAf[256];

    if (blockIdx.x < CB) {  // ---- count role: 8 coalesced strided edges/thread
        const int t = blockIdx.x * 256 + threadIdx.x;   // 0..100095
        #pragma unroll
        for (int j = 0; j < 8; ++j) {
            const int e = t + j * (CB * 256);
            if (e < N_EDGES) {
                pos8[e] = atomicAdd(&rowcnt[row[e]], 1);
                atomicAdd(&colcnt[col[e]], 1);
            }
        }
        return;
    }

    // ---- gemm role: 64 nodes x 128 feats ----
    const int q = blockIdx.x - CB;
    const int tid  = threadIdx.x;
    const int wave = tid >> 6, lane = tid & 63;
    const int l16  = lane & 15, quad = lane >> 4;
    const int row0 = q * 64;

    f32x4 acc[4][2] = {};

    int sr = row0 + wave * 16 + l16;
    if (sr >= N_NODES) sr = N_NODES - 1;
    const float* xrow = x + (size_t)sr * F_IN + (quad << 3);

    for (int c = 0; c < F_IN / 32; ++c) {
        float4 a = *(const float4*)(xrow + c * 32);
        float4 b = *(const float4*)(xrow + c * 32 + 4);
        uint4 fr;
        fr.x = pkbf(a.x, a.y); fr.y = pkbf(a.z, a.w);
        fr.z = pkbf(b.x, b.y); fr.w = pkbf(b.z, b.w);
        XAf[tid] = fr;
        __syncthreads();

        uint4 t0 = w1f[(size_t)(c * 8 + wave * 2 + 0) * 64 + lane];
        uint4 t1 = w1f[(size_t)(c * 8 + wave * 2 + 1) * 64 + lane];
        s16x8 bf0 = *(s16x8*)&t0, bf1 = *(s16x8*)&t1;

        #pragma unroll
        for (int i = 0; i < 4; ++i) {
            uint4 ta = XAf[i * 64 + lane];
            s16x8 af = *(s16x8*)&ta;
            acc[i][0] = __builtin_amdgcn_mfma_f32_16x16x32_bf16(af, bf0, acc[i][0], 0, 0, 0);
            acc[i][1] = __builtin_amdgcn_mfma_f32_16x16x32_bf16(af, bf1, acc[i][1], 0, 0, 0);
        }
        __syncthreads();
    }

    const int n0 = wave * 32;
    #pragma unroll
    for (int i = 0; i < 4; ++i) {
        #pragma unroll
        for (int p = 0; p < 4; ++p) {
            int gr = row0 + i * 16 + quad * 4 + p;
            if (gr < N_NODES) {
                #pragma unroll
                for (int u = 0; u < 2; ++u)
                    h1s[(size_t)gr * HIDDEN + n0 + u * 16 + l16] =
                        (unsigned short)bf16r(acc[i][u][p]);
            }
        }
    }
}

// ---------------- scan of rowcnt -> rowptr, plus dinv from colcnt ----------
__global__ void scan_blocks_kernel(const int* __restrict__ rowcnt,
                                   const int* __restrict__ colcnt,
                                   float* __restrict__ dinv,
                                   int* __restrict__ rowptr, int* __restrict__ partials) {
    __shared__ int s[256];
    const int tid = threadIdx.x;
    const int i = blockIdx.x * 256 + tid;
    const int v = (i < N_NODES) ? rowcnt[i] : 0;
    s[tid] = v;
    __syncthreads();
    #pragma unroll
    for (int off = 1; off < 256; off <<= 1) {
        int t = (tid >= off) ? s[tid - off] : 0;
        __syncthreads();
        s[tid] += t;
        __syncthreads();
    }
    if (i < N_NODES) {
        rowptr[i] = s[tid] - v;
        dinv[i] = rsqrtf(1.0f + (float)colcnt[i]);  // +1 self-loop
    }
    if (tid == 255) partials[blockIdx.x] = s[255];
}

// scan_add with internal prefix reduction of partials (replaces scan_partials)
__global__ void scan_add_kernel(int* __restrict__ rowptr, const int* __restrict__ partials) {
    __shared__ int s[256];
    const int tid = threadIdx.x;
    s[tid] = (tid < blockIdx.x) ? partials[tid] : 0;   // blockIdx < NSCAN <= 256
    __syncthreads();
    #pragma unroll
    for (int off = 128; off > 0; off >>= 1) {
        if (tid < off) s[tid] += s[tid + off];
        __syncthreads();
    }
    const int base = s[0];
    const int i = blockIdx.x * 256 + tid;
    if (i < N_NODES) rowptr[i] += base;
    if (i == 0) rowptr[N_NODES] = N_EDGES;
}

// ---------------- CSR placement (no atomics) ----------------
__global__ void place_kernel(const int* __restrict__ row, const int* __restrict__ col,
                             const int* __restrict__ rowptr, const int* __restrict__ pos8,
                             int* __restrict__ ecol) {
    int e = blockIdx.x * 256 + threadIdx.x;
    if (e < N_EDGES) ecol[rowptr[row[e]] + pos8[e]] = col[e];
}

// ---- gather1: agg1(bf16) = relu(dinv[r]*(sum dinv[c]*h1[c] + dinv[r]*h1[r]) + b1)
__global__ __launch_bounds__(256) void gather1_kernel(
    const int* __restrict__ rowptr, const int* __restrict__ ecol,
    const float* __restrict__ dinv, const unsigned* __restrict__ h1u,
    const float* __restrict__ b1, unsigned* __restrict__ agg1u)
{
    const int wave = threadIdx.x >> 6, lane = threadIdx.x & 63;
    const int r = blockIdx.x * 4 + wave;
    if (r >= N_NODES) return;
    const int start = rowptr[r], end = rowptr[r + 1];

    float ax = 0.f, ay = 0.f, bx = 0.f, by = 0.f;
    float cx = 0.f, cy = 0.f, dx = 0.f, dy = 0.f;
    if (start < end) {
        for (int e = start; e < end; e += 4) {
            const int i1 = min(e + 1, end - 1), i2 = min(e + 2, end - 1), i3 = min(e + 3, end - 1);
            const int c0 = ecol[e], c1 = ecol[i1], c2 = ecol[i2], c3 = ecol[i3];
            const float d0 = dinv[c0];
            const float d1 = (e + 1 < end) ? dinv[c1] : 0.f;
            const float d2 = (e + 2 < end) ? dinv[c2] : 0.f;
            const float d3 = (e + 3 < end) ? dinv[c3] : 0.f;
            unsigned u0 = h1u[(size_t)c0 * 64 + lane];
            unsigned u1 = h1u[(size_t)c1 * 64 + lane];
            unsigned u2 = h1u[(size_t)c2 * 64 + lane];
            unsigned u3 = h1u[(size_t)c3 * 64 + lane];
            ax = fmaf(bflo(u0), d0, ax); ay = fmaf(bfhi(u0), d0, ay);
            bx = fmaf(bflo(u1), d1, bx); by = fmaf(bfhi(u1), d1, by);
            cx = fmaf(bflo(u2), d2, cx); cy = fmaf(bfhi(u2), d2, cy);
            dx = fmaf(bflo(u3), d3, dx); dy = fmaf(bfhi(u3), d3, dy);
        }
    }
    const float s = dinv[r];
    unsigned us = h1u[(size_t)r * 64 + lane];
    float sx = (ax + bx) + (cx + dx) + bflo(us) * s;
    float sy = (ay + by) + (cy + dy) + bfhi(us) * s;
    const float2 bb = *(const float2*)&b1[lane * 2];
    float ox = fmaxf(fmaf(s, sx, bb.x), 0.f);
    float oy = fmaxf(fmaf(s, sy, bb.y), 0.f);
    agg1u[(size_t)r * 64 + lane] = pkbf(ox, oy);
}

// ---------------- GEMM2 (MFMA): h2b[N,40]bf16 = (agg1 @ W2) * dinv[row] ----
__global__ __launch_bounds__(256) void gemm2_kernel(
    const uint4* __restrict__ agg1q, const uint4* __restrict__ w2f,
    const float* __restrict__ dinv, unsigned short* __restrict__ h2b)
{
    __shared__ uint4 XAf[512];
    const int tid  = threadIdx.x;
    const int wave = tid >> 6, lane = tid & 63;
    const int l16  = lane & 15, quad = lane >> 4;
    const int row0 = blockIdx.x * 128;

    f32x4 acc[2][3] = {};

    int r1 = row0 + wave * 16 + l16;        if (r1 >= N_NODES) r1 = N_NODES - 1;
    int r2 = row0 + (4 + wave) * 16 + l16;  if (r2 >= N_NODES) r2 = N_NODES - 1;

    for (int c = 0; c < 4; ++c) {
        XAf[tid]       = agg1q[(size_t)r1 * 16 + c * 4 + quad];
        XAf[tid + 256] = agg1q[(size_t)r2 * 16 + c * 4 + quad];
        __syncthreads();

        s16x8 bf[3];
        #pragma unroll
        for (int u = 0; u < 3; ++u) {
            uint4 t = w2f[(size_t)(c * 3 + u) * 64 + lane];
            bf[u] = *(s16x8*)&t;
        }
        #pragma unroll
        for (int i = 0; i < 2; ++i) {
            uint4 ta = XAf[(wave * 2 + i) * 64 + lane];
            s16x8 af = *(s16x8*)&ta;
            #pragma unroll
            for (int u = 0; u < 3; ++u)
                acc[i][u] = __builtin_amdgcn_mfma_f32_16x16x32_bf16(af, bf[u], acc[i][u], 0, 0, 0);
        }
        __syncthreads();
    }

    #pragma unroll
    for (int i = 0; i < 2; ++i) {
        #pragma unroll
        for (int p = 0; p < 4; ++p) {
            int gr = row0 + (wave * 2 + i) * 16 + quad * 4 + p;
            if (gr < N_NODES) {
                float s = dinv[gr];
                #pragma unroll
                for (int u = 0; u < 3; ++u) {
                    int ncol = u * 16 + l16;
                    if (ncol < N_CLASSES)
                        h2b[(size_t)gr * N_CLASSES + ncol] =
                            (unsigned short)bf16r(acc[i][u][p] * s);
                }
            }
        }
    }
}

// ---------------- gather2: out = dinv[r]*(sum h2b[c] + h2b[r]) + b2 --------
// 20 lanes per edge (2 bf16 feats/lane), 3 edges per iteration, shfl combine.
__global__ __launch_bounds__(256) void gather2_kernel(
    const int* __restrict__ rowptr, const int* __restrict__ ecol,
    const float* __restrict__ dinv, const unsigned* __restrict__ h2u,
    const float* __restrict__ b2, float* __restrict__ out)
{
    const int wave = threadIdx.x >> 6, lane = threadIdx.x & 63;
    const int r = blockIdx.x * 4 + wave;
    if (r >= N_NODES) return;
    const int g = lane / 20;        // 0..3 (g==3 lanes idle in the loop)
    const int j = lane - g * 20;    // 0..19
    const int start = rowptr[r], end = rowptr[r + 1];

    float sx = 0.f, sy = 0.f;
    if (g < 3 && start < end) {
        for (int e = start; e < end; e += 3) {
            const int ee = e + g;
            const int c = ecol[min(ee, end - 1)];
            unsigned u = h2u[(size_t)c * 20 + j];
            u = (ee < end) ? u : 0u;
            sx += bflo(u); sy += bfhi(u);
        }
    }
    // combine the 3 groups into lanes 0..19
    float tx = sx + __shfl(sx, lane + 20, 64) + __shfl(sx, lane + 40, 64);
    float ty = sy + __shfl(sy, lane + 20, 64) + __shfl(sy, lane + 40, 64);
    if (lane < 20) {
        unsigned us = h2u[(size_t)r * 20 + j];
        tx += bflo(us); ty += bfhi(us);
        const float2 bb = *(const float2*)&b2[2 * j];
        float2 o;
        o.x = fmaf(dinv[r], tx, bb.x);
        o.y = fmaf(dinv[r], ty, bb.y);
        *(float2*)&out[(size_t)r * N_CLASSES + 2 * j] = o;
    }
}

extern "C" void kernel_launch(void* const* d_in, const int* in_sizes, int n_in,
                              void* d_out, int out_size, void* d_ws, size_t ws_size,
                              hipStream_t stream)
{
    const float* x  = (const float*)d_in[0];
    const int*   ei = (const int*)d_in[1];
    const float* W1 = (const float*)d_in[2];
    const float* b1 = (const float*)d_in[3];
    const float* W2 = (const float*)d_in[4];
    const float* b2 = (const float*)d_in[5];
    const int* row = ei;            // destinations
    const int* col = ei + N_EDGES;  // sources

    // ---- workspace layout, float-slot units (4 B each) ----
    float* ws = (float*)d_ws;
    int*   rowcnt   = (int*)(ws);                 // [0,        65536)   \ one memset
    int*   colcnt   = (int*)(ws + 65536);         // [65536,   131072)   /
    float* dinv     = ws + 131072;                // [131072,  196608)
    int*   rowptr   = (int*)(ws + 196608);        // [196608,  262144)  need 50001
    int*   partials = (int*)(ws + 262144);        // [262144,  270336)
    int*   pos8     = (int*)(ws + 270336);        // [270336, 1089536)
    int*   ecol     = (int*)(ws + 1089536);       // [1089536,1908736)
    uint4* w1f      = (uint4*)(ws + 1908736);     // [1908736,1941504)  8192 uint4
    uint4* w2f      = (uint4*)(ws + 1941504);     // [1941504,1944576)  768 uint4
    unsigned short* h1s = (unsigned short*)(ws + 1944576);  // [1944576,5144576) 3.2M slots
    unsigned*       h1u = (unsigned*)h1s;
    unsigned* agg1u = (unsigned*)(ws + 5144576);            // [5144576,8344576) 3.2M slots
    uint4*    agg1q = (uint4*)agg1u;
    unsigned short* h2b = (unsigned short*)(ws + 8344576);  // 50000*40 bf16 = 1M slots
    unsigned*       h2u = (unsigned*)h2b;
    float*    out   = (float*)d_out;

    hipMemsetAsync(rowcnt, 0, 2 * 65536 * sizeof(int), stream);
    prep_kernel<<<35, 256, 0, stream>>>(W1, W2, w1f, w2f);

    fused_kernel<<<CB + 782, 256, 0, stream>>>(x, w1f, h1s, row, col, rowcnt, colcnt, pos8);

    scan_blocks_kernel<<<NSCAN, 256, 0, stream>>>(rowcnt, colcnt, dinv, rowptr, partials);
    scan_add_kernel<<<NSCAN, 256, 0, stream>>>(rowptr, partials);
    place_kernel<<<3125, 256, 0, stream>>>(row, col, rowptr, pos8, ecol);

    gather1_kernel<<<N_NODES / 4, 256, 0, stream>>>(rowptr, ecol, dinv, h1u, b1, agg1u);
    gemm2_kernel<<<(N_NODES + 127) / 128, 256, 0, stream>>>(agg1q, w2f, dinv, h2b);
    gather2_kernel<<<N_NODES / 4, 256, 0, stream>>>(rowptr, ecol, dinv, h2u, b2, out);
}

// Round 8
// 310.533 us; speedup vs baseline: 1.0693x; 1.0693x over previous
//
#include <hip/hip_runtime.h>
#include <hip/hip_bf16.h>

#define N_NODES 50000
#define N_EDGES 800000
#define F_IN 512
#define HIDDEN 128
#define N_CLASSES 40
#define NSCAN 196     // ceil(50000/256)

#define CB 391        // count blocks (391*256*8 >= 800000)
#define NSLICE 64     // edge slices for hist role
#define SLICE_E 12500 // edges per slice (64*12500 = 800000)
#define EIGHTH_N 6250 // nodes per eighth (8*6250 = 50000)
#define HB (NSLICE*8) // 512 hist blocks
#define GB 782        // gemm blocks ceil(50000/64)

typedef __attribute__((ext_vector_type(4))) float f32x4;
typedef __attribute__((ext_vector_type(8))) short s16x8;

// manual RNE f32 -> bf16
__device__ __forceinline__ unsigned bf16r(float f) {
    unsigned u = __float_as_uint(f);
    return (u + 0x7fffu + ((u >> 16) & 1u)) >> 16;
}
__device__ __forceinline__ unsigned pkbf(float lo, float hi) {
    return bf16r(lo) | (bf16r(hi) << 16);
}
__device__ __forceinline__ float bflo(unsigned u) { return __uint_as_float(u << 16); }
__device__ __forceinline__ float bfhi(unsigned u) { return __uint_as_float(u & 0xffff0000u); }

// ---------------- prep: pack W1/W2 into MFMA B-fragment layout (bf16) ------
__global__ void prep_kernel(const float* __restrict__ W1, const float* __restrict__ W2,
                            uint4* __restrict__ w1f, uint4* __restrict__ w2f) {
    int f = blockIdx.x * 256 + threadIdx.x;
    if (f < 8192) {
        int lane = f & 63, u = (f >> 6) & 7, c = f >> 9;
        int k0 = c * 32 + ((lane >> 4) << 3), n = u * 16 + (lane & 15);
        float v[8];
        #pragma unroll
        for (int j = 0; j < 8; ++j) v[j] = W1[(size_t)(k0 + j) * HIDDEN + n];
        uint4 o;
        o.x = pkbf(v[0], v[1]); o.y = pkbf(v[2], v[3]);
        o.z = pkbf(v[4], v[5]); o.w = pkbf(v[6], v[7]);
        w1f[f] = o;
    } else if (f < 8960) {
        int g = f - 8192;
        int lane = g & 63, u = (g >> 6) % 3, c = g / 192;
        int k0 = c * 32 + ((lane >> 4) << 3), n = u * 16 + (lane & 15);
        float v[8];
        #pragma unroll
        for (int j = 0; j < 8; ++j)
            v[j] = (n < N_CLASSES) ? W2[(size_t)(k0 + j) * N_CLASSES + n] : 0.0f;
        uint4 o;
        o.x = pkbf(v[0], v[1]); o.y = pkbf(v[2], v[3]);
        o.z = pkbf(v[4], v[5]); o.w = pkbf(v[6], v[7]);
        w2f[g] = o;
    }
}

// ---- fused: count (391) + col-histogram (512) + GEMM1 (782) ----
// count: pos8[e]=atomicAdd(rowcnt[row],1)  (only 800k global atomics remain)
// hist : per-(slice,eighth) LDS histogram of col -> scratch16[s][node] (no atomics)
// gemm : h1[N,128]bf16 = x @ W1  (MFMA)
__global__ __launch_bounds__(256) void fused_kernel(
    const float* __restrict__ x, const uint4* __restrict__ w1f,
    unsigned short* __restrict__ h1s,
    const int* __restrict__ row, const int* __restrict__ col,
    int* __restrict__ rowcnt, int* __restrict__ pos8,
    unsigned* __restrict__ scratch32)
{
    __shared__ __align__(16) unsigned lds_u[3200];  // 12.8 KB: hist h32 / gemm XAf

    if (blockIdx.x < CB) {  // ---- count role ----
        const int t = blockIdx.x * 256 + threadIdx.x;   // 0..100095
        #pragma unroll
        for (int j = 0; j < 8; ++j) {
            const int e = t + j * (CB * 256);
            if (e < N_EDGES) pos8[e] = atomicAdd(&rowcnt[row[e]], 1);
        }
        return;
    }

    if (blockIdx.x < CB + HB) {  // ---- hist role ----
        const int hb = blockIdx.x - CB;   // 0..511
        const int s  = hb & (NSLICE - 1); // slice
        const int q  = hb >> 6;           // eighth
        const int lo = q * EIGHTH_N;
        for (int i = threadIdx.x; i < EIGHTH_N / 2; i += 256) lds_u[i] = 0u;
        __syncthreads();
        const int e0 = s * SLICE_E;
        for (int i = threadIdx.x; i < SLICE_E; i += 256) {
            const int c = col[e0 + i];
            const int lc = c - lo;
            if ((unsigned)lc < (unsigned)EIGHTH_N)
                atomicAdd(&lds_u[lc >> 1], 1u << ((lc & 1) * 16));
        }
        __syncthreads();
        // flush: scratch16[s][node] as u32 pairs -> contiguous 12.5 KB
        unsigned* dst = scratch32 + (size_t)s * (N_NODES / 2) + q * (EIGHTH_N / 2);
        for (int w = threadIdx.x; w < EIGHTH_N / 2; w += 256) dst[w] = lds_u[w];
        return;
    }

    // ---- gemm role: 64 nodes x 128 feats ----
    uint4* XAf = (uint4*)lds_u;
    const int q = blockIdx.x - CB - HB;
    const int tid  = threadIdx.x;
    const int wave = tid >> 6, lane = tid & 63;
    const int l16  = lane & 15, quad = lane >> 4;
    const int row0 = q * 64;

    f32x4 acc[4][2] = {};

    int sr = row0 + wave * 16 + l16;
    if (sr >= N_NODES) sr = N_NODES - 1;
    const float* xrow = x + (size_t)sr * F_IN + (quad << 3);

    for (int c = 0; c < F_IN / 32; ++c) {
        float4 a = *(const float4*)(xrow + c * 32);
        float4 b = *(const float4*)(xrow + c * 32 + 4);
        uint4 fr;
        fr.x = pkbf(a.x, a.y); fr.y = pkbf(a.z, a.w);
        fr.z = pkbf(b.x, b.y); fr.w = pkbf(b.z, b.w);
        XAf[tid] = fr;
        __syncthreads();

        uint4 t0 = w1f[(size_t)(c * 8 + wave * 2 + 0) * 64 + lane];
        uint4 t1 = w1f[(size_t)(c * 8 + wave * 2 + 1) * 64 + lane];
        s16x8 bf0 = *(s16x8*)&t0, bf1 = *(s16x8*)&t1;

        #pragma unroll
        for (int i = 0; i < 4; ++i) {
            uint4 ta = XAf[i * 64 + lane];
            s16x8 af = *(s16x8*)&ta;
            acc[i][0] = __builtin_amdgcn_mfma_f32_16x16x32_bf16(af, bf0, acc[i][0], 0, 0, 0);
            acc[i][1] = __builtin_amdgcn_mfma_f32_16x16x32_bf16(af, bf1, acc[i][1], 0, 0, 0);
        }
        __syncthreads();
    }

    const int n0 = wave * 32;
    #pragma unroll
    for (int i = 0; i < 4; ++i) {
        #pragma unroll
        for (int p = 0; p < 4; ++p) {
            int gr = row0 + i * 16 + quad * 4 + p;
            if (gr < N_NODES) {
                #pragma unroll
                for (int u = 0; u < 2; ++u)
                    h1s[(size_t)gr * HIDDEN + n0 + u * 16 + l16] =
                        (unsigned short)bf16r(acc[i][u][p]);
            }
        }
    }
}

// ---------------- scan: rowptr (block-local) + dinv from scratch ----------
__global__ void scan_blocks_kernel(const int* __restrict__ rowcnt,
                                   const unsigned short* __restrict__ scratch16,
                                   float* __restrict__ dinv,
                                   int* __restrict__ rowptr, int* __restrict__ partials) {
    __shared__ int s[256];
    const int tid = threadIdx.x;
    const int i = blockIdx.x * 256 + tid;
    const int v = (i < N_NODES) ? rowcnt[i] : 0;
    s[tid] = v;
    __syncthreads();
    #pragma unroll
    for (int off = 1; off < 256; off <<= 1) {
        int t = (tid >= off) ? s[tid - off] : 0;
        __syncthreads();
        s[tid] += t;
        __syncthreads();
    }
    if (i < N_NODES) {
        rowptr[i] = s[tid] - v;
        unsigned deg = 0;
        #pragma unroll 8
        for (int sl = 0; sl < NSLICE; ++sl)
            deg += scratch16[(size_t)sl * N_NODES + i];
        dinv[i] = rsqrtf(1.0f + (float)deg);  // +1 self-loop
    }
    if (tid == 255) partials[blockIdx.x] = s[255];
}

// scan_add with internal prefix reduction of partials
__global__ void scan_add_kernel(int* __restrict__ rowptr, const int* __restrict__ partials) {
    __shared__ int s[256];
    const int tid = threadIdx.x;
    s[tid] = (tid < blockIdx.x) ? partials[tid] : 0;   // blockIdx < NSCAN <= 256
    __syncthreads();
    #pragma unroll
    for (int off = 128; off > 0; off >>= 1) {
        if (tid < off) s[tid] += s[tid + off];
        __syncthreads();
    }
    const int base = s[0];
    const int i = blockIdx.x * 256 + tid;
    if (i < N_NODES) rowptr[i] += base;
    if (i == 0) rowptr[N_NODES] = N_EDGES;
}

// ---------------- CSR placement (no atomics) ----------------
__global__ void place_kernel(const int* __restrict__ row, const int* __restrict__ col,
                             const int* __restrict__ rowptr, const int* __restrict__ pos8,
                             int* __restrict__ ecol) {
    int e = blockIdx.x * 256 + threadIdx.x;
    if (e < N_EDGES) ecol[rowptr[row[e]] + pos8[e]] = col[e];
}

// ---- gather1: agg1(bf16) = relu(dinv[r]*(sum dinv[c]*h1[c] + dinv[r]*h1[r]) + b1)
// one wave per node, 8-edge unroll for MLP.
__global__ __launch_bounds__(256) void gather1_kernel(
    const int* __restrict__ rowptr, const int* __restrict__ ecol,
    const float* __restrict__ dinv, const unsigned* __restrict__ h1u,
    const float* __restrict__ b1, unsigned* __restrict__ agg1u)
{
    const int wave = threadIdx.x >> 6, lane = threadIdx.x & 63;
    const int r = blockIdx.x * 4 + wave;
    if (r >= N_NODES) return;
    const int start = rowptr[r], end = rowptr[r + 1];

    float accx[8] = {}, accy[8] = {};
    if (start < end) {
        for (int e = start; e < end; e += 8) {
            int cs[8]; float ds[8]; unsigned us[8];
            #pragma unroll
            for (int j = 0; j < 8; ++j) cs[j] = ecol[min(e + j, end - 1)];
            #pragma unroll
            for (int j = 0; j < 8; ++j) ds[j] = (e + j < end) ? dinv[cs[j]] : 0.f;
            #pragma unroll
            for (int j = 0; j < 8; ++j) us[j] = h1u[(size_t)cs[j] * 64 + lane];
            #pragma unroll
            for (int j = 0; j < 8; ++j) {
                accx[j] = fmaf(bflo(us[j]), ds[j], accx[j]);
                accy[j] = fmaf(bfhi(us[j]), ds[j], accy[j]);
            }
        }
    }
    const float s = dinv[r];
    unsigned uself = h1u[(size_t)r * 64 + lane];
    float sx = ((accx[0] + accx[1]) + (accx[2] + accx[3])) +
               ((accx[4] + accx[5]) + (accx[6] + accx[7])) + bflo(uself) * s;
    float sy = ((accy[0] + accy[1]) + (accy[2] + accy[3])) +
               ((accy[4] + accy[5]) + (accy[6] + accy[7])) + bfhi(uself) * s;
    const float2 bb = *(const float2*)&b1[lane * 2];
    float ox = fmaxf(fmaf(s, sx, bb.x), 0.f);
    float oy = fmaxf(fmaf(s, sy, bb.y), 0.f);
    agg1u[(size_t)r * 64 + lane] = pkbf(ox, oy);
}

// ---------------- GEMM2 (MFMA): h2b[N,40]bf16 = (agg1 @ W2) * dinv[row] ----
__global__ __launch_bounds__(256) void gemm2_kernel(
    const uint4* __restrict__ agg1q, const uint4* __restrict__ w2f,
    const float* __restrict__ dinv, unsigned short* __restrict__ h2b)
{
    __shared__ uint4 XAf[512];
    const int tid  = threadIdx.x;
    const int wave = tid >> 6, lane = tid & 63;
    const int l16  = lane & 15, quad = lane >> 4;
    const int row0 = blockIdx.x * 128;

    f32x4 acc[2][3] = {};

    int r1 = row0 + wave * 16 + l16;        if (r1 >= N_NODES) r1 = N_NODES - 1;
    int r2 = row0 + (4 + wave) * 16 + l16;  if (r2 >= N_NODES) r2 = N_NODES - 1;

    for (int c = 0; c < 4; ++c) {
        XAf[tid]       = agg1q[(size_t)r1 * 16 + c * 4 + quad];
        XAf[tid + 256] = agg1q[(size_t)r2 * 16 + c * 4 + quad];
        __syncthreads();

        s16x8 bf[3];
        #pragma unroll
        for (int u = 0; u < 3; ++u) {
            uint4 t = w2f[(size_t)(c * 3 + u) * 64 + lane];
            bf[u] = *(s16x8*)&t;
        }
        #pragma unroll
        for (int i = 0; i < 2; ++i) {
            uint4 ta = XAf[(wave * 2 + i) * 64 + lane];
            s16x8 af = *(s16x8*)&ta;
            #pragma unroll
            for (int u = 0; u < 3; ++u)
                acc[i][u] = __builtin_amdgcn_mfma_f32_16x16x32_bf16(af, bf[u], acc[i][u], 0, 0, 0);
        }
        __syncthreads();
    }

    #pragma unroll
    for (int i = 0; i < 2; ++i) {
        #pragma unroll
        for (int p = 0; p < 4; ++p) {
            int gr = row0 + (wave * 2 + i) * 16 + quad * 4 + p;
            if (gr < N_NODES) {
                float s = dinv[gr];
                #pragma unroll
                for (int u = 0; u < 3; ++u) {
                    int ncol = u * 16 + l16;
                    if (ncol < N_CLASSES)
                        h2b[(size_t)gr * N_CLASSES + ncol] =
                            (unsigned short)bf16r(acc[i][u][p] * s);
                }
            }
        }
    }
}

// ---------------- gather2: out = dinv[r]*(sum h2b[c] + h2b[r]) + b2 --------
__global__ __launch_bounds__(256) void gather2_kernel(
    const int* __restrict__ rowptr, const int* __restrict__ ecol,
    const float* __restrict__ dinv, const unsigned* __restrict__ h2u,
    const float* __restrict__ b2, float* __restrict__ out)
{
    const int wave = threadIdx.x >> 6, lane = threadIdx.x & 63;
    const int r = blockIdx.x * 4 + wave;
    if (r >= N_NODES) return;
    const int g = lane / 20;        // 0..3 (g==3 lanes idle in the loop)
    const int j = lane - g * 20;    // 0..19
    const int start = rowptr[r], end = rowptr[r + 1];

    float sx = 0.f, sy = 0.f;
    if (g < 3 && start < end) {
        for (int e = start; e < end; e += 3) {
            const int ee = e + g;
            const int c = ecol[min(ee, end - 1)];
            unsigned u = h2u[(size_t)c * 20 + j];
            u = (ee < end) ? u : 0u;
            sx += bflo(u); sy += bfhi(u);
        }
    }
    float tx = sx + __shfl(sx, lane + 20, 64) + __shfl(sx, lane + 40, 64);
    float ty = sy + __shfl(sy, lane + 20, 64) + __shfl(sy, lane + 40, 64);
    if (lane < 20) {
        unsigned us = h2u[(size_t)r * 20 + j];
        tx += bflo(us); ty += bfhi(us);
        const float2 bb = *(const float2*)&b2[2 * j];
        float2 o;
        o.x = fmaf(dinv[r], tx, bb.x);
        o.y = fmaf(dinv[r], ty, bb.y);
        *(float2*)&out[(size_t)r * N_CLASSES + 2 * j] = o;
    }
}

extern "C" void kernel_launch(void* const* d_in, const int* in_sizes, int n_in,
                              void* d_out, int out_size, void* d_ws, size_t ws_size,
                              hipStream_t stream)
{
    const float* x  = (const float*)d_in[0];
    const int*   ei = (const int*)d_in[1];
    const float* W1 = (const float*)d_in[2];
    const float* b1 = (const float*)d_in[3];
    const float* W2 = (const float*)d_in[4];
    const float* b2 = (const float*)d_in[5];
    const int* row = ei;            // destinations
    const int* col = ei + N_EDGES;  // sources

    // ---- workspace layout, float-slot units (4 B each) ----
    float* ws = (float*)d_ws;
    int*   rowcnt   = (int*)(ws);                  // [0,       65536)  memset
    float* dinv     = ws + 65536;                  // [65536,  131072)
    int*   rowptr   = (int*)(ws + 131072);         // [131072, 196608) need 50001
    int*   partials = (int*)(ws + 196608);         // [196608, 204800)
    int*   pos8     = (int*)(ws + 204800);         // [204800,1024000)
    int*   ecol     = (int*)(ws + 1024000);        // [1024000,1843200)
    unsigned* scratch32 = (unsigned*)(ws + 1843200);           // 1.6M u32 = 64x50000 u16
    unsigned short* scratch16 = (unsigned short*)scratch32;
    uint4* w1f      = (uint4*)(ws + 3443200);      // 8192 uint4
    uint4* w2f      = (uint4*)(ws + 3475968);      // 768 uint4
    unsigned short* h1s = (unsigned short*)(ws + 3479040);     // 3.2M slots
    unsigned*       h1u = (unsigned*)h1s;
    unsigned* agg1u = (unsigned*)(ws + 6679040);               // 3.2M slots
    uint4*    agg1q = (uint4*)agg1u;
    unsigned short* h2b = (unsigned short*)(ws + 9879040);     // 1M slots
    unsigned*       h2u = (unsigned*)h2b;
    float*    out   = (float*)d_out;

    hipMemsetAsync(rowcnt, 0, 65536 * sizeof(int), stream);
    prep_kernel<<<35, 256, 0, stream>>>(W1, W2, w1f, w2f);

    fused_kernel<<<CB + HB + GB, 256, 0, stream>>>(x, w1f, h1s, row, col,
                                                   rowcnt, pos8, scratch32);

    scan_blocks_kernel<<<NSCAN, 256, 0, stream>>>(rowcnt, scratch16, dinv, rowptr, partials);
    scan_add_kernel<<<NSCAN, 256, 0, stream>>>(rowptr, partials);
    place_kernel<<<3125, 256, 0, stream>>>(row, col, rowptr, pos8, ecol);

    gather1_kernel<<<N_NODES / 4, 256, 0, stream>>>(rowptr, ecol, dinv, h1u, b1, agg1u);
    gemm2_kernel<<<(N_NODES + 127) / 128, 256, 0, stream>>>(agg1q, w2f, dinv, h2b);
    gather2_kernel<<<N_NODES / 4, 256, 0, stream>>>(rowptr, ecol, dinv, h2u, b2, out);
}